// Round 2
// baseline (104.613 us; speedup 1.0000x reference)
//
#include <hip/hip_runtime.h>

#define OUT_W 320
#define OUT_H 240
#define NPIX (OUT_W * OUT_H)
#define S_IN 128
#define SLICE (S_IN * S_IN)
#define VOLC (S_IN * S_IN * S_IN)
#define ZSEG 4          // waves (z-segments) per pixel group
#define ZLEN 64         // ray samples per segment  (4*64 = 256)

// One block = 64 pixels x 4 z-segments (256 threads).
// lane (0..63) = pixel within group, wave id = z-segment.
// Segment results (T, wsum, accRGB) combine associatively in LDS.
__global__ __launch_bounds__(256) void raycast_kernel(const float* __restrict__ vol,
                                                      float* __restrict__ out) {
    const int lane = threadIdx.x & 63;
    const int seg  = threadIdx.x >> 6;
    const int pix  = blockIdx.x * 64 + lane;
    const int x = pix % OUT_W;
    const int y = pix / OUT_W;

    // ---- per-pixel bilinear (y,x) setup: grid_sample align_corners=False, zero pad ----
    float fx = (float)x * (128.0f / 319.0f) - 0.5f;
    int   ix0 = (int)floorf(fx);
    float wx1 = fx - (float)ix0;
    float wx0 = 1.0f - wx1;
    float wxa = (ix0 >= 0)       ? wx0 : 0.0f;
    float wxb = (ix0 + 1 < S_IN) ? wx1 : 0.0f;
    int   cx0 = max(ix0, 0);
    int   cx1 = min(ix0 + 1, S_IN - 1);

    float fy = (float)y * (128.0f / 239.0f) - 0.5f;
    int   iy0 = (int)floorf(fy);
    float wy1 = fy - (float)iy0;
    float wy0 = 1.0f - wy1;
    float wya = (iy0 >= 0)       ? wy0 : 0.0f;
    float wyb = (iy0 + 1 < S_IN) ? wy1 : 0.0f;
    int   cy0 = max(iy0, 0);
    int   cy1 = min(iy0 + 1, S_IN - 1);

    const float w00 = wya * wxa, w01 = wya * wxb, w10 = wyb * wxa, w11 = wyb * wxb;
    const int o00 = cy0 * S_IN + cx0;
    const int o01 = cy0 * S_IN + cx1;
    const int o10 = cy1 * S_IN + cx0;
    const int o11 = cy1 * S_IN + cx1;

    // bilinear sample of all 4 channels at input slice k
    auto bilin = [&](int k, float s[4]) {
        const float* p = vol + k * SLICE;
#pragma unroll
        for (int c = 0; c < 4; ++c) {
            const float* q = p + c * VOLC;
            s[c] = w00 * q[o00] + w01 * q[o01] + w10 * q[o10] + w11 * q[o11];
        }
    };

    // ---- z-segment ray march with slice-sample caching ----
    const int zbeg = seg * ZLEN;
    float s0[4], s1[4];
    int kcur = (int)floorf((float)zbeg * (128.0f / 255.0f) - 0.5f);
    if (kcur >= 0) bilin(kcur, s0);
    else {
#pragma unroll
        for (int c = 0; c < 4; ++c) s0[c] = 0.0f;
    }
    if (kcur + 1 < S_IN) bilin(kcur + 1, s1);
    else {
#pragma unroll
        for (int c = 0; c < 4; ++c) s1[c] = 0.0f;
    }

    float T = 1.0f, wsum = 0.0f, a0 = 0.0f, a1 = 0.0f, a2 = 0.0f;
    for (int z = zbeg; z < zbeg + ZLEN; ++z) {
        float fz  = (float)z * (128.0f / 255.0f) - 0.5f;
        int   i0  = (int)floorf(fz);
        float wz1 = fz - (float)i0;
        float wz0 = 1.0f - wz1;
        if (i0 != kcur) {            // wave-uniform branch (z is uniform in the wave)
            kcur = i0;
#pragma unroll
            for (int c = 0; c < 4; ++c) s0[c] = s1[c];
            if (kcur + 1 < S_IN) bilin(kcur + 1, s1);
            else {
#pragma unroll
                for (int c = 0; c < 4; ++c) s1[c] = 0.0f;
            }
        }
        float wa = (i0 >= 0) ? wz0 : 0.0f;   // zero-pad below volume
        float r  = wa * s0[0] + wz1 * s1[0];
        float g  = wa * s0[1] + wz1 * s1[1];
        float b  = wa * s0[2] + wz1 * s1[2];
        float dv = wa * s0[3] + wz1 * s1[3];
        float d  = dv * (100.0f / 256.0f);   // DENSITY_FACTOR / RAY_SAMPLES
        T *= (1.0f - d);                      // cumprod is INCLUSIVE in the reference
        float w = d * T;
        wsum += w;
        a0 += w * r; a1 += w * g; a2 += w * b;
    }

    // ---- combine 4 segments per pixel ----
    __shared__ float shT[ZSEG][64], shW[ZSEG][64], sh0[ZSEG][64], sh1[ZSEG][64], sh2[ZSEG][64];
    shT[seg][lane] = T;
    shW[seg][lane] = wsum;
    sh0[seg][lane] = a0;
    sh1[seg][lane] = a1;
    sh2[seg][lane] = a2;
    __syncthreads();

    if (threadIdx.x < 64) {
        float Tg = 1.0f, ws = 0.0f, r0 = 0.0f, r1 = 0.0f, r2 = 0.0f;
#pragma unroll
        for (int s = 0; s < ZSEG; ++s) {
            r0 += Tg * sh0[s][lane];
            r1 += Tg * sh1[s][lane];
            r2 += Tg * sh2[s][lane];
            ws += Tg * shW[s][lane];
            Tg *= shT[s][lane];
        }
        float alpha = 1.0f - Tg;
        float inv   = alpha / (ws + 1e-8f);
        out[0 * NPIX + pix] = r0 * inv;
        out[1 * NPIX + pix] = r1 * inv;
        out[2 * NPIX + pix] = r2 * inv;
        out[3 * NPIX + pix] = alpha;
    }
}

extern "C" void kernel_launch(void* const* d_in, const int* in_sizes, int n_in,
                              void* d_out, int out_size, void* d_ws, size_t ws_size,
                              hipStream_t stream) {
    (void)in_sizes; (void)n_in; (void)out_size; (void)d_ws; (void)ws_size;
    const float* vol = (const float*)d_in[0];
    float* out = (float*)d_out;
    const int nblocks = NPIX / 64;   // 1200 blocks x 256 threads
    raycast_kernel<<<nblocks, 256, 0, stream>>>(vol, out);
}